// Round 2
// baseline (1046.834 us; speedup 1.0000x reference)
//
#include <hip/hip_runtime.h>
#include <math.h>

// 4-byte-aligned float4 for the misaligned output regions (d_out+1, d_out+16777218)
typedef float f4u __attribute__((ext_vector_type(4), aligned(4)));

#define DIM 256
#define KCB 1024
#define PERP_OFF 16777217
#define ENC_OFF  16777218

// ---------------------------------------------------------------------------
// numpy pairwise sum-of-squares of a 128-element block (numpy pairwise_sum,
// PW_BLOCKSIZE=128 path): 8 accumulators r[j]=sum of a[j],a[j+8],...,a[j+120]
// (sequential), combined ((r0+r1)+(r2+r3))+((r4+r5)+(r6+r7)). Each square is
// rounded separately (numpy materializes xf**2 first) -> __fmul_rn/__fadd_rn
// to forbid fma contraction. For n=256 numpy splits 128+128 and adds.
// ---------------------------------------------------------------------------
__device__ __forceinline__ float np_sumsq128(const float* a, int stride) {
  float r[8];
  #pragma unroll
  for (int j = 0; j < 8; ++j) { float v = a[j * stride]; r[j] = __fmul_rn(v, v); }
  #pragma unroll
  for (int i = 8; i < 128; i += 8) {
    #pragma unroll
    for (int j = 0; j < 8; ++j) {
      float v = a[(i + j) * stride];
      r[j] = __fadd_rn(r[j], __fmul_rn(v, v));
    }
  }
  float s01 = __fadd_rn(r[0], r[1]);
  float s23 = __fadd_rn(r[2], r[3]);
  float s45 = __fadd_rn(r[4], r[5]);
  float s67 = __fadd_rn(r[6], r[7]);
  return __fadd_rn(__fadd_rn(s01, s23), __fadd_rn(s45, s67));
}

// ---------------------------------------------------------------------------
// k_insq: in_sq[n] = np.sum(xf[n]**2) in exact numpy pairwise order.
// xf[n][c] = x[b, c, h, w], n = b*4096 + h*64 + w  ->  stride 4096 over c.
// Lanes = consecutive w -> each c-step is a coalesced 256B read. grid 256x256
// ---------------------------------------------------------------------------
__global__ __launch_bounds__(256)
void k_insq(const float* __restrict__ x, float* __restrict__ in_sq) {
  const int n = blockIdx.x * 256 + threadIdx.x;
  const int b = n >> 12;
  const int hw = n & 4095;
  const float* p = x + b * 1048576 + hw;
  float h0 = np_sumsq128(p, 4096);
  float h1 = np_sumsq128(p + 128 * 4096, 4096);
  in_sq[n] = __fadd_rn(h0, h1);
}

// ---------------------------------------------------------------------------
// k_cbsq: cb_sq[k] = np.sum(codebook[k]**2), exact numpy pairwise order.
// One thread per row. grid 4x256
// ---------------------------------------------------------------------------
__global__ __launch_bounds__(256)
void k_cbsq(const float* __restrict__ cb, float* __restrict__ cb_sq) {
  const int k = blockIdx.x * 256 + threadIdx.x;
  const float* p = cb + k * DIM;
  float h0 = np_sumsq128(p, 1);
  float h1 = np_sumsq128(p + 128, 1);
  cb_sq[k] = __fadd_rn(h0, h1);
}

// ---------------------------------------------------------------------------
// k_prep: transposed codebook cb_t[c][k] (for L1-hot gathers in k_xq),
// zero counts. grid 1024 x 64 (one wave per codebook row)
// ---------------------------------------------------------------------------
__global__ __launch_bounds__(64)
void k_prep(const float* __restrict__ cb, float* __restrict__ cb_t,
            int* __restrict__ counts) {
  const int k = blockIdx.x;
  const int l = threadIdx.x;                  // 0..63
  float4 v = ((const float4*)(cb + k * DIM))[l];
  cb_t[(l*4+0)*KCB + k] = v.x;
  cb_t[(l*4+1)*KCB + k] = v.y;
  cb_t[(l*4+2)*KCB + k] = v.z;
  cb_t[(l*4+3)*KCB + k] = v.w;
  if (l == 0) counts[k] = 0;
}

// ---------------------------------------------------------------------------
// k_argmin: replicate np fp32 semantics: for each vector n,
//   dist_k = fl32( fl32(in_sq[n] + cb_sq[k]) - fl32(2 * dot) )
// with dot accumulated as a single sequential fp32 FMA chain over d=0..255
// (matches BLAS sgemm microkernel accumulation order), argmin with
// lowest-index tie-break (np.argmin first-occurrence rule).
// block = 256 threads, tile = 32 vectors x all K. LDS: Xs 32KB + Es 32KB.
// Thread tile 4 vectors x 8 codes; tn = t&7, tk = t>>3. grid 2048 x 256
// ---------------------------------------------------------------------------
__global__ __launch_bounds__(256, 2)
void k_argmin(const float* __restrict__ x, const float* __restrict__ cb,
              const float* __restrict__ cb_sq, const float* __restrict__ in_sq,
              int* __restrict__ best_idx) {
  __shared__ float Xs[256 * 32];   // [d][n]
  __shared__ float Es[32 * 256];   // [dd][k]
  const int t = threadIdx.x;
  const int g = blockIdx.x;
  const int b   = g >> 7;          // 128 blocks per batch image
  const int rem = g & 127;
  const int h   = rem >> 1;
  const int w0  = (rem & 1) << 5;  // 0 or 32
  const float* xbase = x + b * 1048576 + h * 64 + w0;

  // stage Xs: thread t loads channel c=t, 32 consecutive w (128B contiguous)
  {
    const float* src = xbase + t * 4096;
    #pragma unroll
    for (int j = 0; j < 8; ++j) {
      float4 v = *(const float4*)(src + j * 4);
      *(float4*)(Xs + t * 32 + j * 4) = v;
    }
  }

  const int tn = t & 7;    // vector group: n_local = tn*4 .. tn*4+3
  const int tk = t >> 3;   // code group:  k = kc + tk*8 .. +7
  // np-exact in_sq for my 4 vectors (n = g*32 + tn*4 + i)
  const float4 isq = *(const float4*)(in_sq + g * 32 + tn * 4);
  const float isqa[4] = {isq.x, isq.y, isq.z, isq.w};

  float bestv[4];
  int   besti[4];
  #pragma unroll
  for (int i = 0; i < 4; ++i) { bestv[i] = 1e30f; besti[i] = 0; }
  __syncthreads();

  for (int kc = 0; kc < KCB; kc += 256) {
    float acc[4][8];
    #pragma unroll
    for (int i = 0; i < 4; ++i)
      #pragma unroll
      for (int j = 0; j < 8; ++j) acc[i][j] = 0.f;

    for (int ds = 0; ds < DIM; ds += 32) {
      // stage Es[dd][k]: thread t owns codebook row kc+t, dims [ds, ds+32)
      {
        const float* src = cb + (kc + t) * DIM + ds;
        #pragma unroll
        for (int j = 0; j < 8; ++j) {
          float4 v = *(const float4*)(src + j * 4);
          Es[(4*j+0)*256 + t] = v.x;
          Es[(4*j+1)*256 + t] = v.y;
          Es[(4*j+2)*256 + t] = v.z;
          Es[(4*j+3)*256 + t] = v.w;
        }
      }
      __syncthreads();
      // d ascends 0..255 across (ds, dd): single sequential fmaf chain per
      // (vector, code) pair — matches BLAS sgemm K-accumulation order.
      #pragma unroll
      for (int dd = 0; dd < 32; ++dd) {
        float4 xv = *(const float4*)(Xs + (ds + dd) * 32 + tn * 4);
        float4 e0 = *(const float4*)(Es + dd * 256 + tk * 8);
        float4 e1 = *(const float4*)(Es + dd * 256 + tk * 8 + 4);
        float xa[4] = {xv.x, xv.y, xv.z, xv.w};
        float ea[8] = {e0.x, e0.y, e0.z, e0.w, e1.x, e1.y, e1.z, e1.w};
        #pragma unroll
        for (int i = 0; i < 4; ++i)
          #pragma unroll
          for (int j = 0; j < 8; ++j)
            acc[i][j] = fmaf(xa[i], ea[j], acc[i][j]);
      }
      __syncthreads();
    }

    // fold chunk into running best with np-quantized dist + first-index ties
    #pragma unroll
    for (int j = 0; j < 8; ++j) {
      const int k = kc + tk * 8 + j;
      const float cs = cb_sq[k];
      #pragma unroll
      for (int i = 0; i < 4; ++i) {
        const float t1   = __fadd_rn(isqa[i], cs);        // fl(in_sq + cb_sq)
        const float t2   = __fmul_rn(2.0f, acc[i][j]);    // exact (x2)
        const float dist = __fsub_rn(t1, t2);             // fl(t1 - t2)
        if (dist < bestv[i] || (dist == bestv[i] && k < besti[i])) {
          bestv[i] = dist; besti[i] = k;
        }
      }
    }
  }

  // cross-tk reduction with index tie-break (Es free after last barrier)
  float* Rv = Es;                  // [32 tk][32 n]
  int*   Ri = (int*)(Es + 1024);   // [32 tk][32 n]
  #pragma unroll
  for (int i = 0; i < 4; ++i) {
    Rv[tk * 32 + tn * 4 + i] = bestv[i];
    Ri[tk * 32 + tn * 4 + i] = besti[i];
  }
  __syncthreads();
  if (t < 32) {
    float bv = Rv[t];
    int   bi = Ri[t];
    #pragma unroll
    for (int r = 1; r < 32; ++r) {
      float v  = Rv[r * 32 + t];
      int   ix = Ri[r * 32 + t];
      if (v < bv || (v == bv && ix < bi)) { bv = v; bi = ix; }
    }
    best_idx[g * 32 + t] = bi;
  }
}

// ---------------------------------------------------------------------------
// k_xq: xq_out[b,c,h,w] = fl(xp + fl(q - xp)) (np two-step), plus per-block
// double partial of sum((q-xp)^2). grid 16384 x 256, 4 elem/thread.
// ---------------------------------------------------------------------------
__global__ __launch_bounds__(256)
void k_xq(const float* __restrict__ x, const float* __restrict__ cb_t,
          const int* __restrict__ best_idx, float* __restrict__ out1,
          double* __restrict__ partials) {
  const int t = threadIdx.x;
  const unsigned e = ((unsigned)blockIdx.x * 256u + (unsigned)t) * 4u;
  const int w = e & 63;
  const int h = (e >> 6) & 63;
  const int c = (e >> 12) & 255;
  const int b = e >> 20;
  const int n = b * 4096 + h * 64 + w;
  const int4  id4 = *(const int4*)(best_idx + n);
  const float4 xp = *(const float4*)(x + e);
  const float* row = cb_t + c * KCB;       // 4KB row -> L1-hot gathers
  const float q0 = row[id4.x], q1 = row[id4.y], q2 = row[id4.z], q3 = row[id4.w];
  const float d0 = __fsub_rn(q0, xp.x), d1 = __fsub_rn(q1, xp.y);
  const float d2 = __fsub_rn(q2, xp.z), d3 = __fsub_rn(q3, xp.w);
  f4u o;
  o.x = __fadd_rn(xp.x, d0); o.y = __fadd_rn(xp.y, d1);
  o.z = __fadd_rn(xp.z, d2); o.w = __fadd_rn(xp.w, d3);
  *(f4u*)(out1 + e) = o;

  double s = (double)(d0*d0) + (double)(d1*d1) + (double)(d2*d2) + (double)(d3*d3);
  #pragma unroll
  for (int off = 32; off > 0; off >>= 1) s += __shfl_down(s, off);
  __shared__ double sm[4];
  if ((t & 63) == 0) sm[t >> 6] = s;
  __syncthreads();
  if (t == 0) partials[blockIdx.x] = (sm[0] + sm[1]) + (sm[2] + sm[3]);
}

// ---------------------------------------------------------------------------
// k_enc: fused zero+scatter of one-hot encodings + histogram.
// 4 rows/block, 64 threads/row; coalesced f4u stores. grid 16384 x 256
// ---------------------------------------------------------------------------
__global__ __launch_bounds__(256)
void k_enc(const int* __restrict__ best_idx, float* __restrict__ enc,
           int* __restrict__ counts) {
  const int t    = threadIdx.x;
  const int row  = blockIdx.x * 4 + (t >> 6);
  const int lane = t & 63;
  const int bi   = best_idx[row];
  float* rbase = enc + (size_t)row * KCB;
  const int target = bi >> 2;
  const int m      = bi & 3;
  #pragma unroll
  for (int j = 0; j < 4; ++j) {
    const int f4i = lane + 64 * j;
    f4u v = {0.f, 0.f, 0.f, 0.f};
    if (f4i == target) {
      if (m == 0) v.x = 1.f; else if (m == 1) v.y = 1.f;
      else if (m == 2) v.z = 1.f; else v.w = 1.f;
    }
    *(f4u*)(rbase + f4i * 4) = v;
  }
  if (lane == 0) atomicAdd(counts + bi, 1);
}

// ---------------------------------------------------------------------------
// k_final: reduce partials -> loss; counts -> perplexity. grid 1 x 256
// ---------------------------------------------------------------------------
__global__ __launch_bounds__(256)
void k_final(const double* __restrict__ partials, const int* __restrict__ counts,
             float* __restrict__ out) {
  const int t = threadIdx.x;
  double s = 0.0;
  for (int i = t; i < 16384; i += 256) s += partials[i];
  #pragma unroll
  for (int off = 32; off > 0; off >>= 1) s += __shfl_down(s, off);
  __shared__ double sm[4];
  if ((t & 63) == 0) sm[t >> 6] = s;
  __syncthreads();
  if (t == 0) {
    const double tot = (sm[0] + sm[1]) + (sm[2] + sm[3]);
    const float mval = (float)(tot / 16777216.0);
    out[0] = mval + 0.25f * mval;            // quantization + beta*embedding
    float ps = 0.f;
    for (int k = 0; k < KCB; ++k) {
      const float p = (float)counts[k] * (1.0f / 65536.0f);
      ps += p * logf(1.0e10f + p);           // faithful to the reference's +1e10
    }
    out[PERP_OFF] = expf(-ps);
  }
}

// ---------------------------------------------------------------------------
extern "C" void kernel_launch(void* const* d_in, const int* in_sizes, int n_in,
                              void* d_out, int out_size, void* d_ws, size_t ws_size,
                              hipStream_t stream) {
  const float* x  = (const float*)d_in[0];   // (16,256,64,64) fp32
  const float* cb = (const float*)d_in[1];   // (1024,256) fp32
  float* out = (float*)d_out;
  char*  ws  = (char*)d_ws;

  int*    counts   = (int*)(ws + 0);          //   4 KB
  int*    best_idx = (int*)(ws + 8192);       // 256 KB
  float*  cb_sq    = (float*)(ws + 270336);   //   4 KB
  float*  cb_t     = (float*)(ws + 274432);   //   1 MB  [c][k]
  double* partials = (double*)(ws + 1323008); // 128 KB
  float*  in_sq    = (float*)(ws + 1454080);  // 256 KB

  k_insq  <<<256, 256, 0, stream>>>(x, in_sq);
  k_cbsq  <<<4, 256, 0, stream>>>(cb, cb_sq);
  k_prep  <<<1024, 64, 0, stream>>>(cb, cb_t, counts);
  k_argmin<<<2048, 256, 0, stream>>>(x, cb, cb_sq, in_sq, best_idx);
  k_xq    <<<16384, 256, 0, stream>>>(x, cb_t, best_idx, out + 1, partials);
  k_enc   <<<16384, 256, 0, stream>>>(best_idx, out + ENC_OFF, counts);
  k_final <<<1, 256, 0, stream>>>(partials, counts, out);
}

// Round 3
// 886.987 us; speedup vs baseline: 1.1802x; 1.1802x over previous
//
#include <hip/hip_runtime.h>
#include <math.h>
#include <stdint.h>

// 4-byte-aligned float4 for the misaligned output regions (d_out+1, d_out+16777218)
typedef float f4u __attribute__((ext_vector_type(4), aligned(4)));

#define DIM 256
#define KCB 1024
#define PERP_OFF 16777217
#define ENC_OFF  16777218

// ---------------------------------------------------------------------------
// numpy pairwise sum-of-squares of a 128-element block (numpy pairwise_sum,
// PW_BLOCKSIZE=128 path): 8 accumulators, combined ((r0+r1)+(r2+r3))+((r4+r5)+(r6+r7)).
// Squares rounded separately -> __fmul_rn/__fadd_rn (no fma contraction).
// ---------------------------------------------------------------------------
__device__ __forceinline__ float np_sumsq128(const float* a, int stride) {
  float r[8];
  #pragma unroll
  for (int j = 0; j < 8; ++j) { float v = a[j * stride]; r[j] = __fmul_rn(v, v); }
  #pragma unroll
  for (int i = 8; i < 128; i += 8) {
    #pragma unroll
    for (int j = 0; j < 8; ++j) {
      float v = a[(i + j) * stride];
      r[j] = __fadd_rn(r[j], __fmul_rn(v, v));
    }
  }
  float s01 = __fadd_rn(r[0], r[1]);
  float s23 = __fadd_rn(r[2], r[3]);
  float s45 = __fadd_rn(r[4], r[5]);
  float s67 = __fadd_rn(r[6], r[7]);
  return __fadd_rn(__fadd_rn(s01, s23), __fadd_rn(s45, s67));
}

// ---------------------------------------------------------------------------
// k_insq: in_sq[n] = np.sum(xf[n]**2) in exact numpy pairwise order. grid 256x256
// ---------------------------------------------------------------------------
__global__ __launch_bounds__(256)
void k_insq(const float* __restrict__ x, float* __restrict__ in_sq) {
  const int n = blockIdx.x * 256 + threadIdx.x;
  const int b = n >> 12;
  const int hw = n & 4095;
  const float* p = x + b * 1048576 + hw;
  float h0 = np_sumsq128(p, 4096);
  float h1 = np_sumsq128(p + 128 * 4096, 4096);
  in_sq[n] = __fadd_rn(h0, h1);
}

// ---------------------------------------------------------------------------
// k_cbsq: cb_sq[k] = np.sum(codebook[k]**2), exact numpy pairwise order. grid 4x256
// ---------------------------------------------------------------------------
__global__ __launch_bounds__(256)
void k_cbsq(const float* __restrict__ cb, float* __restrict__ cb_sq) {
  const int k = blockIdx.x * 256 + threadIdx.x;
  const float* p = cb + k * DIM;
  float h0 = np_sumsq128(p, 1);
  float h1 = np_sumsq128(p + 128, 1);
  cb_sq[k] = __fadd_rn(h0, h1);
}

// ---------------------------------------------------------------------------
// k_prep: transposed codebook cb_t[d][k] (feeds k_argmin Es staging AND k_epi
// gathers), zero counts. grid 1024 x 64
// ---------------------------------------------------------------------------
__global__ __launch_bounds__(64)
void k_prep(const float* __restrict__ cb, float* __restrict__ cb_t,
            int* __restrict__ counts) {
  const int k = blockIdx.x;
  const int l = threadIdx.x;                  // 0..63
  float4 v = ((const float4*)(cb + k * DIM))[l];
  cb_t[(l*4+0)*KCB + k] = v.x;
  cb_t[(l*4+1)*KCB + k] = v.y;
  cb_t[(l*4+2)*KCB + k] = v.z;
  cb_t[(l*4+3)*KCB + k] = v.w;
  if (l == 0) counts[k] = 0;
}

// ---------------------------------------------------------------------------
// k_argmin v2: np-exact dist = fl(fl(in_sq+cb_sq) - fl(2*dot)), dot = strict
// sequential fp32 fma chain d=0..255 (bitwise identical to R2 which passed
// with absmax 0). Block: 32 n x 1024 k. Thread tile 8n x 16k (acc 128 VGPR).
// tn = t&3 (n = tn*8..+7), tk = t>>2 (k = 4*tk+c+256*j, c<4, j<4) -> Es reads
// are 16B-stride lane-contiguous (conflict-free; old layout was 64B stride =
// 8-way). Es staged from cb_t[d][k] via global_load_lds width 16 (wave-uniform
// LDS base + lane*16). LDS: Xs 32KB + Es 32KB. grid 2048 x 256.
// ---------------------------------------------------------------------------
__global__ __launch_bounds__(256, 2)
void k_argmin(const float* __restrict__ x, const float* __restrict__ cb_t,
              const float* __restrict__ cb_sq, const float* __restrict__ in_sq,
              int* __restrict__ best_idx) {
  __shared__ float Xs[DIM * 32];      // [d][n]  32KB
  __shared__ float Es[8 * KCB];       // [dd][k] 32KB
  const int t = threadIdx.x;
  const int g = blockIdx.x;
  const int b   = g >> 7;
  const int rem = g & 127;
  const int h   = rem >> 1;
  const int w0  = (rem & 1) << 5;
  const float* xbase = x + b * 1048576 + h * 64 + w0;

  // stage Xs: thread t = channel, 32 consecutive w (128B contiguous)
  {
    const float* src = xbase + t * 4096;
    #pragma unroll
    for (int j = 0; j < 8; ++j)
      *(float4*)(Xs + t * 32 + j * 4) = *(const float4*)(src + j * 4);
  }

  const int tn   = t & 3;    // n-group: n_local = tn*8 .. +7
  const int tk   = t >> 2;   // k-group: k = 4*tk + c + 256*j
  const int wv   = t >> 6;   // wave id 0..3
  const int lane = t & 63;

  float acc[8][16];
  #pragma unroll
  for (int i = 0; i < 8; ++i)
    #pragma unroll
    for (int j = 0; j < 16; ++j) acc[i][j] = 0.f;

  for (int ds = 0; ds < DIM; ds += 8) {
    __syncthreads();   // prior compute (and Xs staging, first iter) done
    // stage Es[dd][k]: wave wv stages k in [wv*256, wv*256+256) for dd=0..7
    #pragma unroll
    for (int dd = 0; dd < 8; ++dd) {
      const float* gsrc = cb_t + (ds + dd) * KCB + wv * 256 + lane * 4;
      float* ldst = Es + dd * KCB + wv * 256;   // wave-uniform; HW adds lane*16B
      __builtin_amdgcn_global_load_lds(
          (const __attribute__((address_space(1))) void*)gsrc,
          (__attribute__((address_space(3))) void*)ldst, 16, 0, 0);
    }
    __syncthreads();   // staging landed (barrier drains vmcnt)
    #pragma unroll
    for (int dd = 0; dd < 8; ++dd) {
      const float4 xv0 = *(const float4*)(Xs + (ds + dd) * 32 + tn * 8);
      const float4 xv1 = *(const float4*)(Xs + (ds + dd) * 32 + tn * 8 + 4);
      const float xa[8] = {xv0.x, xv0.y, xv0.z, xv0.w,
                           xv1.x, xv1.y, xv1.z, xv1.w};
      float ea[16];
      #pragma unroll
      for (int jj = 0; jj < 4; ++jj) {
        const float4 ev = *(const float4*)(Es + dd * KCB + jj * 256 + tk * 4);
        ea[jj*4+0] = ev.x; ea[jj*4+1] = ev.y;
        ea[jj*4+2] = ev.z; ea[jj*4+3] = ev.w;
      }
      #pragma unroll
      for (int i = 0; i < 8; ++i)
        #pragma unroll
        for (int j = 0; j < 16; ++j)
          acc[i][j] = fmaf(xa[i], ea[j], acc[i][j]);
    }
  }

  // per-thread fold over its 16 k (explicit k tie-break -> order-independent)
  const int n0 = g * 32 + tn * 8;
  const float4 isq0 = *(const float4*)(in_sq + n0);
  const float4 isq1 = *(const float4*)(in_sq + n0 + 4);
  const float isqa[8] = {isq0.x, isq0.y, isq0.z, isq0.w,
                         isq1.x, isq1.y, isq1.z, isq1.w};
  float bestv[8]; int besti[8];
  #pragma unroll
  for (int i = 0; i < 8; ++i) { bestv[i] = 1e30f; besti[i] = 0; }
  #pragma unroll
  for (int jj = 0; jj < 4; ++jj) {
    const float4 cs4 = *(const float4*)(cb_sq + jj * 256 + tk * 4);
    const float csa[4] = {cs4.x, cs4.y, cs4.z, cs4.w};
    #pragma unroll
    for (int c = 0; c < 4; ++c) {
      const int k = jj * 256 + tk * 4 + c;
      #pragma unroll
      for (int i = 0; i < 8; ++i) {
        const float t1   = __fadd_rn(isqa[i], csa[c]);
        const float t2   = __fmul_rn(2.0f, acc[i][jj*4+c]);
        const float dist = __fsub_rn(t1, t2);
        if (dist < bestv[i] || (dist == bestv[i] && k < besti[i])) {
          bestv[i] = dist; besti[i] = k;
        }
      }
    }
  }

  // cross-thread reduce over the 64 tk-groups (Es free after barrier)
  __syncthreads();
  float* Rv = Es;                  // [64 tk][32 n]
  int*   Ri = (int*)(Es + 2048);   // [64 tk][32 n]
  #pragma unroll
  for (int i = 0; i < 8; ++i) {
    Rv[tk * 32 + tn * 8 + i] = bestv[i];
    Ri[tk * 32 + tn * 8 + i] = besti[i];
  }
  __syncthreads();
  if (t < 32) {
    float bv = Rv[t]; int bi = Ri[t];
    for (int r = 1; r < 64; ++r) {
      float v  = Rv[r * 32 + t];
      int   ix = Ri[r * 32 + t];
      if (v < bv || (v == bv && ix < bi)) { bv = v; bi = ix; }
    }
    best_idx[g * 32 + t] = bi;
  }
}

// ---------------------------------------------------------------------------
// k_epi: fused epilogue, one block per (b,h) = 64 vectors.
//  - encodings: thread t owns one-hot columns 4t..4t+3 for all 64 rows ->
//    fully coalesced 4KB f4u store bursts.
//  - histogram: 64 atomics/block.
//  - xq (straight-through, fp32 np two-step) + double loss partial.
// grid 1024 x 256.
// ---------------------------------------------------------------------------
__global__ __launch_bounds__(256)
void k_epi(const float* __restrict__ x, const float* __restrict__ cb_t,
           const int* __restrict__ best_idx, float* __restrict__ out1,
           float* __restrict__ enc, int* __restrict__ counts,
           double* __restrict__ partials) {
  const int t  = threadIdx.x;
  const int bh = blockIdx.x;           // 0..1023
  const int b  = bh >> 6, h = bh & 63;
  __shared__ int idxs[64];
  if (t < 64) {
    const int myidx = best_idx[bh * 64 + t];
    idxs[t] = myidx;
    atomicAdd(counts + myidx, 1);
  }
  __syncthreads();

  // encodings
  {
    float* base = enc + (size_t)bh * 65536 + t * 4;
    #pragma unroll 8
    for (int r = 0; r < 64; ++r) {
      const int bi = idxs[r];
      f4u v = {0.f, 0.f, 0.f, 0.f};
      if ((bi >> 2) == t) {
        if ((bi & 3) == 0) v.x = 1.f; else if ((bi & 3) == 1) v.y = 1.f;
        else if ((bi & 3) == 2) v.z = 1.f; else v.w = 1.f;
      }
      *(f4u*)(base + r * 1024) = v;
    }
  }

  // xq + loss: thread handles w4..w4+3 across 16 channels
  const int w4 = (t & 15) * 4;
  const int cg = t >> 4;               // 0..15
  const int i0 = idxs[w4], i1 = idxs[w4+1], i2 = idxs[w4+2], i3 = idxs[w4+3];
  double s = 0.0;
  #pragma unroll 4
  for (int j = 0; j < 16; ++j) {
    const int c = cg * 16 + j;
    const size_t off = ((size_t)b << 20) + ((size_t)c << 12) + (h << 6) + w4;
    const float4 xp = *(const float4*)(x + off);
    const float* row = cb_t + c * KCB;   // 4KB row, L1-hot gathers
    const float q0 = row[i0], q1 = row[i1], q2 = row[i2], q3 = row[i3];
    const float d0 = __fsub_rn(q0, xp.x), d1 = __fsub_rn(q1, xp.y);
    const float d2 = __fsub_rn(q2, xp.z), d3 = __fsub_rn(q3, xp.w);
    f4u o;
    o.x = __fadd_rn(xp.x, d0); o.y = __fadd_rn(xp.y, d1);
    o.z = __fadd_rn(xp.z, d2); o.w = __fadd_rn(xp.w, d3);
    *(f4u*)(out1 + off) = o;
    s += (double)(d0*d0) + (double)(d1*d1) + (double)(d2*d2) + (double)(d3*d3);
  }
  #pragma unroll
  for (int off = 32; off > 0; off >>= 1) s += __shfl_down(s, off);
  __shared__ double sm[4];
  if ((t & 63) == 0) sm[t >> 6] = s;
  __syncthreads();
  if (t == 0) partials[bh] = (sm[0] + sm[1]) + (sm[2] + sm[3]);
}

// ---------------------------------------------------------------------------
// k_final: reduce 1024 partials -> loss; counts -> perplexity (parallel; the
// +1e10-in-log makes the value ~1e-10, far below threshold sensitivity).
// grid 1 x 256
// ---------------------------------------------------------------------------
__global__ __launch_bounds__(256)
void k_final(const double* __restrict__ partials, const int* __restrict__ counts,
             float* __restrict__ out) {
  const int t = threadIdx.x;
  double s = 0.0;
  #pragma unroll
  for (int i = 0; i < 4; ++i) s += partials[t + i * 256];
  #pragma unroll
  for (int off = 32; off > 0; off >>= 1) s += __shfl_down(s, off);
  __shared__ double sm[4];
  __shared__ float smf[4];
  if ((t & 63) == 0) sm[t >> 6] = s;

  float ps = 0.f;
  #pragma unroll
  for (int i = 0; i < 4; ++i) {
    const float p = (float)counts[t + i * 256] * (1.0f / 65536.0f);
    ps += p * logf(1.0e10f + p);         // faithful to the reference's +1e10
  }
  #pragma unroll
  for (int off = 32; off > 0; off >>= 1) ps += __shfl_down(ps, off);
  if ((t & 63) == 0) smf[t >> 6] = ps;
  __syncthreads();
  if (t == 0) {
    const double tot = (sm[0] + sm[1]) + (sm[2] + sm[3]);
    const float mval = (float)(tot / 16777216.0);
    out[0] = mval + 0.25f * mval;        // quantization + beta*embedding
    out[PERP_OFF] = expf(-((smf[0] + smf[1]) + (smf[2] + smf[3])));
  }
}

// ---------------------------------------------------------------------------
extern "C" void kernel_launch(void* const* d_in, const int* in_sizes, int n_in,
                              void* d_out, int out_size, void* d_ws, size_t ws_size,
                              hipStream_t stream) {
  const float* x  = (const float*)d_in[0];   // (16,256,64,64) fp32
  const float* cb = (const float*)d_in[1];   // (1024,256) fp32
  float* out = (float*)d_out;
  char*  ws  = (char*)d_ws;

  int*    counts   = (int*)(ws + 0);          //   4 KB
  int*    best_idx = (int*)(ws + 8192);       // 256 KB
  float*  cb_sq    = (float*)(ws + 270336);   //   4 KB
  float*  cb_t     = (float*)(ws + 274432);   //   1 MB  [d][k]
  double* partials = (double*)(ws + 1323008); //   8 KB (1024 doubles)
  float*  in_sq    = (float*)(ws + 1454080);  // 256 KB

  k_insq  <<<256, 256, 0, stream>>>(x, in_sq);
  k_cbsq  <<<4, 256, 0, stream>>>(cb, cb_sq);
  k_prep  <<<1024, 64, 0, stream>>>(cb, cb_t, counts);
  k_argmin<<<2048, 256, 0, stream>>>(x, cb_t, cb_sq, in_sq, best_idx);
  k_epi   <<<1024, 256, 0, stream>>>(x, cb_t, best_idx, out + 1,
                                     out + ENC_OFF, counts, partials);
  k_final <<<1, 256, 0, stream>>>(partials, counts, out);
}